// Round 1
// baseline (6165.990 us; speedup 1.0000x reference)
//
#include <hip/hip_runtime.h>

// ---------------- common helpers ----------------

using bf16x8 = __attribute__((ext_vector_type(8))) short;   // 8 bf16 (4 VGPRs)
using f32x4  = __attribute__((ext_vector_type(4))) float;   // 4 fp32 acc

__device__ __forceinline__ ushort f2bf(float f) {            // fp32 -> bf16 RNE
    unsigned u = __float_as_uint(f);
    u += 0x7FFFu + ((u >> 16) & 1u);
    return (ushort)(u >> 16);
}
__device__ __forceinline__ float bf2f(ushort h) {
    return __uint_as_float((unsigned)h << 16);
}

// block = 256 threads (4 waves). Reduces two values across the block.
__device__ __forceinline__ void blockReduce2(float& a, float& b, float* sh) {
#pragma unroll
    for (int off = 32; off > 0; off >>= 1) {
        a += __shfl_down(a, off, 64);
        b += __shfl_down(b, off, 64);
    }
    int wave = threadIdx.x >> 6, lane = threadIdx.x & 63;
    __syncthreads();                       // protect prior use of sh
    if (lane == 0) { sh[wave] = a; sh[4 + wave] = b; }
    __syncthreads();
    a = sh[0] + sh[1] + sh[2] + sh[3];
    b = sh[4] + sh[5] + sh[6] + sh[7];
}

// ---------------- weight transpose (fp32 [K][N] -> bf16 [N][K]) ----------------
// grid: (N/32, K/32, L), block (32,8). K,N multiples of 32.
__global__ void transpose_w_k(const float* __restrict__ in, ushort* __restrict__ out,
                              int K, int N) {
    __shared__ float tile[32][33];
    size_t zoff = (size_t)blockIdx.z * K * N;
    in += zoff; out += zoff;
    int n0 = blockIdx.x * 32, k0 = blockIdx.y * 32;
    int tx = threadIdx.x, ty = threadIdx.y;
#pragma unroll
    for (int i = 0; i < 4; i++)
        tile[ty + i * 8][tx] = in[(size_t)(k0 + ty + i * 8) * N + n0 + tx];
    __syncthreads();
#pragma unroll
    for (int i = 0; i < 4; i++)
        out[(size_t)(n0 + ty + i * 8) * K + k0 + tx] = f2bf(tile[tx][ty + i * 8]);
}

// ---------------- V transpose per (b,h): v[b,s,h,d] -> vT[z=(b,h)][d][s(pad 224)] ----------
// grid: (7, 2, 384), block (32,8). zero-pads s in [197,224)
__global__ void transpose_v_k(const ushort* __restrict__ v, ushort* __restrict__ vT) {
    __shared__ ushort tile[32][33];
    int z = blockIdx.z, b = z / 12, hh = z % 12;
    int s0 = blockIdx.x * 32, d0 = blockIdx.y * 32;
    int tx = threadIdx.x, ty = threadIdx.y;
#pragma unroll
    for (int i = 0; i < 4; i++) {
        int s = s0 + ty + i * 8;
        tile[ty + i * 8][tx] =
            (s < 197) ? v[((size_t)(b * 197 + s)) * 768 + hh * 64 + d0 + tx] : (ushort)0;
    }
    __syncthreads();
#pragma unroll
    for (int i = 0; i < 4; i++) {
        int d = d0 + ty + i * 8;
        vT[(size_t)z * 64 * 224 + (size_t)d * 224 + s0 + tx] = tile[tx][ty + i * 8];
    }
}

// ---------------- patchify: img [32,3,224,224] -> patches bf16 [6272][768] -----------
// e = (p1*16+p2)*3 + c  (p1 p2 c order). grid 18816 x 256.
__global__ __launch_bounds__(256) void patchify_k(const float* __restrict__ img,
                                                  ushort* __restrict__ patches) {
    int idx = blockIdx.x * 256 + threadIdx.x;
    int e = idx % 768, pr = idx / 768;
    int b = pr / 196, p = pr % 196;
    int ph = p / 14, pw = p % 14;
    int c = e % 3, pe = e / 3;
    int p1 = pe >> 4, p2 = pe & 15;
    float v = img[((size_t)(b * 3 + c) * 224 + ph * 16 + p1) * 224 + pw * 16 + p2];
    patches[idx] = f2bf(v);
}

// ---------------- assemble x = [cls | patch_tokens + posenc] -> x fp32 + bf16 --------
// grid 18912 x 256 over 6304*768 elements
__global__ __launch_bounds__(256) void assemble_k(const float* __restrict__ y,
                                                  const float* __restrict__ cls,
                                                  float* __restrict__ x,
                                                  ushort* __restrict__ xb) {
    int idx = blockIdx.x * 256 + threadIdx.x;
    int e = idx % 768, rr = idx / 768;
    int b = rr / 197, s = rr % 197;
    float val;
    if (s == 0) {
        val = cls[e];
    } else {
        int p = s - 1, iy = p / 14, ix = p % 14;
        int j = e % 192, g = e / 192;
        float om = powf(10000.f, -(float)j * (1.0f / 191.0f));
        float arg = ((g & 2) ? (float)iy : (float)ix) * om;
        float pe = (g & 1) ? cosf(arg) : sinf(arg);
        val = y[(size_t)(b * 196 + p) * 768 + e] + pe;
    }
    x[idx] = val;
    xb[idx] = f2bf(val);
}

// ---------------- fused residual + LN (+ optional second LN for MLP input) -----------
// x_new = LN(y + x, g1, b1) -> x (fp32), xb (bf16); if doSecond: xf = bf16(LN(x_new, gf, bf))
// grid 6304 x 256
__global__ __launch_bounds__(256) void ln_kernel(const float* __restrict__ y,
                                                 float* __restrict__ x,
                                                 ushort* __restrict__ xb,
                                                 ushort* __restrict__ xf,
                                                 const float* __restrict__ g1,
                                                 const float* __restrict__ b1,
                                                 const float* __restrict__ gf,
                                                 const float* __restrict__ bfv,
                                                 int doSecond) {
    __shared__ float red[8];
    int row = blockIdx.x, tid = threadIdx.x;
    const float* yr = y + (size_t)row * 768;
    float* xr = x + (size_t)row * 768;
    float v0[3], s = 0.f, ss = 0.f;
#pragma unroll
    for (int i = 0; i < 3; i++) {
        int c = tid + i * 256;
        float t = yr[c] + xr[c];
        v0[i] = t; s += t; ss += t * t;
    }
    blockReduce2(s, ss, red);
    float m = s * (1.f / 768.f);
    float var = ss * (1.f / 768.f) - m * m;
    float rstd = rsqrtf(var + 1e-5f);
    float s2 = 0.f, ss2 = 0.f, w0[3];
#pragma unroll
    for (int i = 0; i < 3; i++) {
        int c = tid + i * 256;
        float xv = (v0[i] - m) * rstd * g1[c] + b1[c];
        w0[i] = xv;
        xr[c] = xv;
        xb[(size_t)row * 768 + c] = f2bf(xv);
        s2 += xv; ss2 += xv * xv;
    }
    if (doSecond) {
        blockReduce2(s2, ss2, red);
        float m2 = s2 * (1.f / 768.f);
        float var2 = ss2 * (1.f / 768.f) - m2 * m2;
        float r2 = rsqrtf(var2 + 1e-5f);
#pragma unroll
        for (int i = 0; i < 3; i++) {
            int c = tid + i * 256;
            xf[(size_t)row * 768 + c] = f2bf((w0[i] - m2) * r2 * gf[c] + bfv[c]);
        }
    }
}

// ---------------- softmax, in-place bf16, rows of [197 valid | 224 padded] ----------
// grid (197, 384), block 64 (one wave per row). Zeros pad cols.
__global__ __launch_bounds__(64) void softmax_k(ushort* __restrict__ logits) {
    int s = blockIdx.x, z = blockIdx.y, lane = threadIdx.x;
    ushort* row = logits + ((size_t)z * 197 + s) * 224;
    float v[4], mx = -1e30f;
#pragma unroll
    for (int i = 0; i < 4; i++) {
        int c = lane + i * 64;
        float t = -1e30f;
        if (c < 197) t = bf2f(row[c]);
        v[i] = t; mx = fmaxf(mx, t);
    }
#pragma unroll
    for (int off = 32; off > 0; off >>= 1) mx = fmaxf(mx, __shfl_xor(mx, off, 64));
    float sum = 0.f;
#pragma unroll
    for (int i = 0; i < 4; i++) {
        int c = lane + i * 64;
        float ev = 0.f;
        if (c < 197) ev = expf(v[i] - mx);
        v[i] = ev; sum += ev;
    }
#pragma unroll
    for (int off = 32; off > 0; off >>= 1) sum += __shfl_xor(sum, off, 64);
    float inv = 1.f / sum;
#pragma unroll
    for (int i = 0; i < 4; i++) {
        int c = lane + i * 64;
        if (c < 224) row[c] = f2bf(c < 197 ? v[i] * inv : 0.f);
    }
}

// ---------------- classifier: out[b][c] = x[b,0,:] . clf_w[:,c] + clf_b[c] ----------
__global__ __launch_bounds__(256) void classifier_k(const float* __restrict__ x,
                                                    const float* __restrict__ w,
                                                    const float* __restrict__ bias,
                                                    float* __restrict__ out) {
    __shared__ float red[8];
    int b = blockIdx.x, tid = threadIdx.x;
    const float* xr = x + (size_t)b * 197 * 768;
    float s0 = 0.f, s1 = 0.f;
    for (int e = tid; e < 768; e += 256) {
        float xv = xr[e];
        s0 += xv * w[2 * e];
        s1 += xv * w[2 * e + 1];
    }
    blockReduce2(s0, s1, red);
    if (tid == 0) {
        out[2 * b] = s0 + bias[0];
        out[2 * b + 1] = s1 + bias[1];
    }
}

// ---------------- NT GEMM: C = act(A[M,K] . BT[N,K]^T * scale + bias) ----------------
// A, BT bf16 row-major; C fp32 or bf16. 256 threads = 4 waves in 2x2 grid,
// each wave a (TM*16)x(TN*16) sub-tile of 16x16x32 bf16 MFMAs. BK=32, K % 32 == 0.
// MODE 0: generic z-strided. MODE 1: QK^T per z=(b*12+h). MODE 2: PV per z.
template <int BM, int BN, int MODE, bool BIAS, bool GELU_ACT, bool OUT_BF16>
__global__ __launch_bounds__(256) void gemm_nt(const ushort* __restrict__ Ab, int lda, long long sAz,
                                               const ushort* __restrict__ Bb, int ldb, long long sBz,
                                               void* __restrict__ Cb, int ldc, long long sCz,
                                               const float* __restrict__ bias,
                                               int M, int N, int K, float scale) {
    constexpr int BK = 32;
    constexpr int LK = BK + 8;           // +8 bf16 pad: keeps 16B align, breaks conflicts
    constexpr int TM = BM / 32, TN = BN / 32;
    __shared__ __align__(16) ushort As[BM * LK];
    __shared__ __align__(16) ushort Bs[BN * LK];

    int z = blockIdx.z;
    const ushort* A = Ab;
    const ushort* B = Bb;
    char* C = (char*)Cb;
    if (MODE == 0) {
        A += (size_t)z * sAz;
        B += (size_t)z * sBz;
        C += (size_t)z * sCz * (OUT_BF16 ? 2 : 4);
    } else if (MODE == 1) {              // QK^T: A=q slice, B=k slice, C=logits[z]
        int b = z / 12, hh = z % 12;
        size_t qo = (size_t)(b * 197) * 768 + hh * 64;
        A += qo; B += qo;
        C += (size_t)z * 197 * 224 * 2;
    } else {                             // PV: A=probs[z], B=vT[z], C=o slice
        int b = z / 12, hh = z % 12;
        A += (size_t)z * 197 * 224;
        B += (size_t)z * 64 * 224;
        C += ((size_t)(b * 197) * 768 + hh * 64) * 2;
    }

    int tid = threadIdx.x;
    int lane = tid & 63, wave = tid >> 6;
    int wr = wave >> 1, wc = wave & 1;
    int qq = lane >> 4, rr = lane & 15;
    int tileM = blockIdx.y * BM, tileN = blockIdx.x * BN;

    f32x4 acc[TM][TN] = {};

    for (int k0 = 0; k0 < K; k0 += BK) {
        // stage A: BM x 32 bf16 (chunks of 8 bf16 = 16B), rows OOB -> 0
        for (int i = tid; i < BM * 4; i += 256) {
            int row = i >> 2, ck = i & 3;
            int gr = tileM + row;
            uint4 val = make_uint4(0, 0, 0, 0);
            if (gr < M) val = *(const uint4*)(A + (size_t)gr * lda + (k0 + ck * 8));
            *(uint4*)(&As[row * LK + ck * 8]) = val;
        }
        // stage B (BT rows = output cols)
        for (int i = tid; i < BN * 4; i += 256) {
            int row = i >> 2, ck = i & 3;
            int gr = tileN + row;
            uint4 val = make_uint4(0, 0, 0, 0);
            if (gr < N) val = *(const uint4*)(B + (size_t)gr * ldb + (k0 + ck * 8));
            *(uint4*)(&Bs[row * LK + ck * 8]) = val;
        }
        __syncthreads();
        bf16x8 af[TM], bfr[TN];
#pragma unroll
        for (int i = 0; i < TM; i++)
            af[i] = *(const bf16x8*)(&As[(wr * TM * 16 + i * 16 + rr) * LK + qq * 8]);
#pragma unroll
        for (int j = 0; j < TN; j++)
            bfr[j] = *(const bf16x8*)(&Bs[(wc * TN * 16 + j * 16 + rr) * LK + qq * 8]);
#pragma unroll
        for (int i = 0; i < TM; i++)
#pragma unroll
            for (int j = 0; j < TN; j++)
                acc[i][j] = __builtin_amdgcn_mfma_f32_16x16x32_bf16(af[i], bfr[j], acc[i][j], 0, 0, 0);
        __syncthreads();
    }

    // epilogue: C/D layout col = lane&15, row = (lane>>4)*4 + reg
#pragma unroll
    for (int i = 0; i < TM; i++) {
        int rowb = tileM + wr * TM * 16 + i * 16 + qq * 4;
#pragma unroll
        for (int j = 0; j < TN; j++) {
            int colg = tileN + wc * TN * 16 + j * 16 + rr;
            if (colg >= N) continue;
            float bv = BIAS ? bias[colg] : 0.0f;
#pragma unroll
            for (int rg = 0; rg < 4; rg++) {
                int rowg = rowb + rg;
                if (rowg >= M) continue;
                float c = acc[i][j][rg] * scale + bv;
                if (GELU_ACT) c = 0.5f * c * (1.0f + erff(c * 0.70710678118654752f));
                if (OUT_BF16)
                    ((ushort*)C)[(size_t)rowg * ldc + colg] = f2bf(c);
                else
                    ((float*)C)[(size_t)rowg * ldc + colg] = c;
            }
        }
    }
}

// ---------------- host ----------------

extern "C" void kernel_launch(void* const* d_in, const int* in_sizes, int n_in,
                              void* d_out, int out_size, void* d_ws, size_t ws_size,
                              hipStream_t stream) {
    const float* img     = (const float*)d_in[0];
    const float* patch_w = (const float*)d_in[1];
    const float* patch_b = (const float*)d_in[2];
    const float* cls_tok = (const float*)d_in[3];
    const float* Wq      = (const float*)d_in[4];
    const float* Wk      = (const float*)d_in[5];
    const float* Wv      = (const float*)d_in[6];
    const float* Wo      = (const float*)d_in[7];
    const float* bo      = (const float*)d_in[8];
    const float* ln1_g   = (const float*)d_in[9];
    const float* ln1_b   = (const float*)d_in[10];
    const float* fln_g   = (const float*)d_in[11];
    const float* fln_b   = (const float*)d_in[12];
    const float* fc1_w   = (const float*)d_in[13];
    const float* fc1_b   = (const float*)d_in[14];
    const float* fc2_w   = (const float*)d_in[15];
    const float* fc2_b   = (const float*)d_in[16];
    const float* ln2_g   = (const float*)d_in[17];
    const float* ln2_b   = (const float*)d_in[18];
    const float* clf_w   = (const float*)d_in[19];
    const float* clf_b   = (const float*)d_in[20];

    const size_t EE = (size_t)768 * 768;     // 589824
    const int MROWS = 32 * 197;              // 6304

    char* ws = (char*)d_ws;
    size_t off = 0;
    auto alloc = [&](size_t bytes) { size_t o = off; off += (bytes + 255) & ~(size_t)255; return o; };
    size_t o_wT     = alloc(48 * EE * 2);                    // [wqT|wkT|wvT|woT] x 12 layers
    size_t o_patchT = alloc(EE * 2);
    size_t o_fc1T   = alloc((size_t)12 * 768 * 3072 * 2);    // [3072][768] per layer
    size_t o_fc2T   = alloc((size_t)12 * 768 * 3072 * 2);    // [768][3072] per layer
    size_t o_patch  = alloc((size_t)6272 * 768 * 2);
    size_t o_x      = alloc((size_t)MROWS * 768 * 4);
    size_t o_xb     = alloc((size_t)MROWS * 768 * 2);
    size_t o_xf     = alloc((size_t)MROWS * 768 * 2);
    size_t o_qkv    = alloc((size_t)3 * MROWS * 768 * 2);
    size_t o_y      = alloc((size_t)MROWS * 768 * 4);
    size_t o_o      = alloc((size_t)MROWS * 768 * 2);
    // attention scratch (logits + vT) unioned with MLP hidden h (time-disjoint)
    size_t logitsB  = (size_t)384 * 197 * 224 * 2;           // 33,890,304
    size_t vTB      = (size_t)384 * 64 * 224 * 2;            // 11,010,048
    size_t hB       = (size_t)MROWS * 3072 * 2;              // 38,731,776
    size_t unionB   = (logitsB + vTB > hB) ? logitsB + vTB : hB;
    size_t o_attn   = alloc(unionB);
    if (off > ws_size) return;                               // ws too small: clean fail

    ushort* wT     = (ushort*)(ws + o_wT);
    ushort* patchT = (ushort*)(ws + o_patchT);
    ushort* fc1T   = (ushort*)(ws + o_fc1T);
    ushort* fc2T   = (ushort*)(ws + o_fc2T);
    ushort* patches= (ushort*)(ws + o_patch);
    float*  x      = (float*)(ws + o_x);
    ushort* xb     = (ushort*)(ws + o_xb);
    ushort* xf     = (ushort*)(ws + o_xf);
    ushort* qkv    = (ushort*)(ws + o_qkv);
    float*  y      = (float*)(ws + o_y);
    ushort* o_     = (ushort*)(ws + o_o);
    ushort* logits = (ushort*)(ws + o_attn);
    ushort* vT     = (ushort*)(ws + o_attn + logitsB);
    ushort* h      = (ushort*)(ws + o_attn);

    dim3 tb(32, 8);
    // weight conversion + transpose to bf16 [N][K]
    transpose_w_k<<<dim3(24, 24, 1),  tb, 0, stream>>>(patch_w, patchT, 768, 768);
    transpose_w_k<<<dim3(24, 24, 12), tb, 0, stream>>>(Wq, wT + 0 * 12 * EE, 768, 768);
    transpose_w_k<<<dim3(24, 24, 12), tb, 0, stream>>>(Wk, wT + 1 * 12 * EE, 768, 768);
    transpose_w_k<<<dim3(24, 24, 12), tb, 0, stream>>>(Wv, wT + 2 * 12 * EE, 768, 768);
    transpose_w_k<<<dim3(24, 24, 12), tb, 0, stream>>>(Wo, wT + 3 * 12 * EE, 768, 768);
    transpose_w_k<<<dim3(96, 24, 12), tb, 0, stream>>>(fc1_w, fc1T, 768, 3072);
    transpose_w_k<<<dim3(24, 96, 12), tb, 0, stream>>>(fc2_w, fc2T, 3072, 768);

    // patch embedding
    patchify_k<<<18816, 256, 0, stream>>>(img, patches);
    gemm_nt<128, 128, 0, true, false, false><<<dim3(6, 49, 1), 256, 0, stream>>>(
        patches, 768, 0, patchT, 768, 0, y, 768, 0, patch_b, 6272, 768, 768, 1.0f);
    assemble_k<<<18912, 256, 0, stream>>>(y, cls_tok, x, xb);

    for (int l = 0; l < 12; ++l) {
        // QKV (z = 0,1,2 selects Wq/Wk/Wv)
        gemm_nt<128, 128, 0, false, false, true><<<dim3(6, 50, 3), 256, 0, stream>>>(
            xb, 768, 0, wT + (size_t)l * EE, 768, (long long)(12 * EE),
            qkv, 768, (long long)MROWS * 768, nullptr, MROWS, 768, 768, 1.0f);
        // V -> vT[z][d][s] (zero-padded to 224)
        transpose_v_k<<<dim3(7, 2, 384), tb, 0, stream>>>(qkv + (size_t)2 * MROWS * 768, vT);
        // logits = (Q K^T) * scale
        gemm_nt<64, 64, 1, false, false, true><<<dim3(4, 4, 384), 256, 0, stream>>>(
            qkv, 768, 0, qkv + (size_t)MROWS * 768, 768, 0,
            logits, 224, 0, nullptr, 197, 197, 64, 0.125f);
        softmax_k<<<dim3(197, 384), 64, 0, stream>>>(logits);
        // O = P V
        gemm_nt<64, 64, 2, false, false, true><<<dim3(1, 4, 384), 256, 0, stream>>>(
            logits, 224, 0, vT, 224, 0, o_, 768, 0, nullptr, 197, 64, 224, 1.0f);
        // o @ Wo + bo -> y
        gemm_nt<128, 128, 0, true, false, false><<<dim3(6, 50, 1), 256, 0, stream>>>(
            o_, 768, 0, wT + (size_t)(36 + l) * EE, 768, 0,
            y, 768, 0, bo + l * 768, MROWS, 768, 768, 1.0f);
        // x = LN(y + x, g1, b1); xf = bf16(LN(x, fln))
        ln_kernel<<<MROWS, 256, 0, stream>>>(y, x, xb, xf, ln1_g + l * 768, ln1_b + l * 768,
                                             fln_g + l * 768, fln_b + l * 768, 1);
        // h = gelu(xf @ w1 + b1)  (bf16 out)
        gemm_nt<128, 128, 0, true, true, true><<<dim3(24, 50, 1), 256, 0, stream>>>(
            xf, 768, 0, fc1T + (size_t)l * 768 * 3072, 768, 0,
            h, 3072, 0, fc1_b + l * 3072, MROWS, 3072, 768, 1.0f);
        // y = h @ w2 + b2
        gemm_nt<128, 128, 0, true, false, false><<<dim3(6, 50, 1), 256, 0, stream>>>(
            h, 3072, 0, fc2T + (size_t)l * 768 * 3072, 3072, 0,
            y, 768, 0, fc2_b + l * 768, MROWS, 768, 3072, 1.0f);
        // x = LN(y + x, g2, b2)
        ln_kernel<<<MROWS, 256, 0, stream>>>(y, x, xb, nullptr, ln2_g + l * 768, ln2_b + l * 768,
                                             nullptr, nullptr, 0);
    }

    classifier_k<<<32, 256, 0, stream>>>(x, clf_w, clf_b, (float*)d_out);
}

// Round 2
// 4699.751 us; speedup vs baseline: 1.3120x; 1.3120x over previous
//
#include <hip/hip_runtime.h>

// ---------------- common helpers ----------------

using bf16x8 = __attribute__((ext_vector_type(8))) short;   // 8 bf16 (4 VGPRs)
using f32x4  = __attribute__((ext_vector_type(4))) float;   // 4 fp32 acc

__device__ __forceinline__ ushort f2bf(float f) {            // fp32 -> bf16 RNE
    unsigned u = __float_as_uint(f);
    u += 0x7FFFu + ((u >> 16) & 1u);
    return (ushort)(u >> 16);
}
__device__ __forceinline__ float bf2f(ushort h) {
    return __uint_as_float((unsigned)h << 16);
}

// async 16B global -> LDS (wave-uniform LDS base + lane*16B)
__device__ __forceinline__ void async_copy16(const ushort* g, ushort* l) {
    __builtin_amdgcn_global_load_lds(
        (const __attribute__((address_space(1))) void*)g,
        (__attribute__((address_space(3))) void*)l, 16, 0, 0);
}

// block = 256 threads (4 waves). Reduces two values across the block.
__device__ __forceinline__ void blockReduce2(float& a, float& b, float* sh) {
#pragma unroll
    for (int off = 32; off > 0; off >>= 1) {
        a += __shfl_down(a, off, 64);
        b += __shfl_down(b, off, 64);
    }
    int wave = threadIdx.x >> 6, lane = threadIdx.x & 63;
    __syncthreads();                       // protect prior use of sh
    if (lane == 0) { sh[wave] = a; sh[4 + wave] = b; }
    __syncthreads();
    a = sh[0] + sh[1] + sh[2] + sh[3];
    b = sh[4] + sh[5] + sh[6] + sh[7];
}

// ---------------- weight transpose (fp32 [K][N] -> bf16 [N][K]) ----------------
// grid: (N/32, K/32, L), block (32,8). K,N multiples of 32.
__global__ void transpose_w_k(const float* __restrict__ in, ushort* __restrict__ out,
                              int K, int N) {
    __shared__ float tile[32][33];
    size_t zoff = (size_t)blockIdx.z * K * N;
    in += zoff; out += zoff;
    int n0 = blockIdx.x * 32, k0 = blockIdx.y * 32;
    int tx = threadIdx.x, ty = threadIdx.y;
#pragma unroll
    for (int i = 0; i < 4; i++)
        tile[ty + i * 8][tx] = in[(size_t)(k0 + ty + i * 8) * N + n0 + tx];
    __syncthreads();
#pragma unroll
    for (int i = 0; i < 4; i++)
        out[(size_t)(n0 + ty + i * 8) * K + k0 + tx] = f2bf(tile[tx][ty + i * 8]);
}

// ---------------- V transpose per (b,h): v[b,s,h,d] -> vT[z=(b,h)][d][s(pad 224)] ----------
// grid: (7, 2, 384), block (32,8). zero-pads s in [197,224)
__global__ void transpose_v_k(const ushort* __restrict__ v, ushort* __restrict__ vT) {
    __shared__ ushort tile[32][33];
    int z = blockIdx.z, b = z / 12, hh = z % 12;
    int s0 = blockIdx.x * 32, d0 = blockIdx.y * 32;
    int tx = threadIdx.x, ty = threadIdx.y;
#pragma unroll
    for (int i = 0; i < 4; i++) {
        int s = s0 + ty + i * 8;
        tile[ty + i * 8][tx] =
            (s < 197) ? v[((size_t)(b * 197 + s)) * 768 + hh * 64 + d0 + tx] : (ushort)0;
    }
    __syncthreads();
#pragma unroll
    for (int i = 0; i < 4; i++) {
        int d = d0 + ty + i * 8;
        vT[(size_t)z * 64 * 224 + (size_t)d * 224 + s0 + tx] = tile[tx][ty + i * 8];
    }
}

// ---------------- patchify: img [32,3,224,224] -> patches bf16 [6272][768] -----------
__global__ __launch_bounds__(256) void patchify_k(const float* __restrict__ img,
                                                  ushort* __restrict__ patches) {
    int idx = blockIdx.x * 256 + threadIdx.x;
    int e = idx % 768, pr = idx / 768;
    int b = pr / 196, p = pr % 196;
    int ph = p / 14, pw = p % 14;
    int c = e % 3, pe = e / 3;
    int p1 = pe >> 4, p2 = pe & 15;
    float v = img[((size_t)(b * 3 + c) * 224 + ph * 16 + p1) * 224 + pw * 16 + p2];
    patches[idx] = f2bf(v);
}

// ---------------- assemble x = [cls | patch_tokens + posenc] -> x fp32 + bf16 --------
__global__ __launch_bounds__(256) void assemble_k(const float* __restrict__ y,
                                                  const float* __restrict__ cls,
                                                  float* __restrict__ x,
                                                  ushort* __restrict__ xb) {
    int idx = blockIdx.x * 256 + threadIdx.x;
    int e = idx % 768, rr = idx / 768;
    int b = rr / 197, s = rr % 197;
    float val;
    if (s == 0) {
        val = cls[e];
    } else {
        int p = s - 1, iy = p / 14, ix = p % 14;
        int j = e % 192, g = e / 192;
        float om = powf(10000.f, -(float)j * (1.0f / 191.0f));
        float arg = ((g & 2) ? (float)iy : (float)ix) * om;
        float pe = (g & 1) ? cosf(arg) : sinf(arg);
        val = y[(size_t)(b * 196 + p) * 768 + e] + pe;
    }
    x[idx] = val;
    xb[idx] = f2bf(val);
}

// ---------------- fused residual + LN (+ optional second LN for MLP input) -----------
__global__ __launch_bounds__(256) void ln_kernel(const float* __restrict__ y,
                                                 float* __restrict__ x,
                                                 ushort* __restrict__ xb,
                                                 ushort* __restrict__ xf,
                                                 const float* __restrict__ g1,
                                                 const float* __restrict__ b1,
                                                 const float* __restrict__ gf,
                                                 const float* __restrict__ bfv,
                                                 int doSecond) {
    __shared__ float red[8];
    int row = blockIdx.x, tid = threadIdx.x;
    const float* yr = y + (size_t)row * 768;
    float* xr = x + (size_t)row * 768;
    float v0[3], s = 0.f, ss = 0.f;
#pragma unroll
    for (int i = 0; i < 3; i++) {
        int c = tid + i * 256;
        float t = yr[c] + xr[c];
        v0[i] = t; s += t; ss += t * t;
    }
    blockReduce2(s, ss, red);
    float m = s * (1.f / 768.f);
    float var = ss * (1.f / 768.f) - m * m;
    float rstd = rsqrtf(var + 1e-5f);
    float s2 = 0.f, ss2 = 0.f, w0[3];
#pragma unroll
    for (int i = 0; i < 3; i++) {
        int c = tid + i * 256;
        float xv = (v0[i] - m) * rstd * g1[c] + b1[c];
        w0[i] = xv;
        xr[c] = xv;
        xb[(size_t)row * 768 + c] = f2bf(xv);
        s2 += xv; ss2 += xv * xv;
    }
    if (doSecond) {
        blockReduce2(s2, ss2, red);
        float m2 = s2 * (1.f / 768.f);
        float var2 = ss2 * (1.f / 768.f) - m2 * m2;
        float r2 = rsqrtf(var2 + 1e-5f);
#pragma unroll
        for (int i = 0; i < 3; i++) {
            int c = tid + i * 256;
            xf[(size_t)row * 768 + c] = f2bf((w0[i] - m2) * r2 * gf[c] + bfv[c]);
        }
    }
}

// ---------------- softmax, in-place bf16, rows of [197 valid | 224 padded] ----------
__global__ __launch_bounds__(64) void softmax_k(ushort* __restrict__ logits) {
    int s = blockIdx.x, z = blockIdx.y, lane = threadIdx.x;
    ushort* row = logits + ((size_t)z * 197 + s) * 224;
    float v[4], mx = -1e30f;
#pragma unroll
    for (int i = 0; i < 4; i++) {
        int c = lane + i * 64;
        float t = -1e30f;
        if (c < 197) t = bf2f(row[c]);
        v[i] = t; mx = fmaxf(mx, t);
    }
#pragma unroll
    for (int off = 32; off > 0; off >>= 1) mx = fmaxf(mx, __shfl_xor(mx, off, 64));
    float sum = 0.f;
#pragma unroll
    for (int i = 0; i < 4; i++) {
        int c = lane + i * 64;
        float ev = 0.f;
        if (c < 197) ev = expf(v[i] - mx);
        v[i] = ev; sum += ev;
    }
#pragma unroll
    for (int off = 32; off > 0; off >>= 1) sum += __shfl_xor(sum, off, 64);
    float inv = 1.f / sum;
#pragma unroll
    for (int i = 0; i < 4; i++) {
        int c = lane + i * 64;
        if (c < 224) row[c] = f2bf(c < 197 ? v[i] * inv : 0.f);
    }
}

// ---------------- classifier ----------------
__global__ __launch_bounds__(256) void classifier_k(const float* __restrict__ x,
                                                    const float* __restrict__ w,
                                                    const float* __restrict__ bias,
                                                    float* __restrict__ out) {
    __shared__ float red[8];
    int b = blockIdx.x, tid = threadIdx.x;
    const float* xr = x + (size_t)b * 197 * 768;
    float s0 = 0.f, s1 = 0.f;
    for (int e = tid; e < 768; e += 256) {
        float xv = xr[e];
        s0 += xv * w[2 * e];
        s1 += xv * w[2 * e + 1];
    }
    blockReduce2(s0, s1, red);
    if (tid == 0) {
        out[2 * b] = s0 + bias[0];
        out[2 * b + 1] = s1 + bias[1];
    }
}

// ---------------- NT GEMM (m97-style): C = act(A[M,K] . BT[N,K]^T * scale + bias) ----
// A, BT bf16 row-major; staging via global_load_lds width=16 into UNPADDED LDS
// (BK=32 -> 64 B/row; one 1KB wave-issue covers 16 rows). OOB rows clamp to the
// last valid row: garbage lands only in C rows/cols that the epilogue discards.
// 256 threads = 4 waves in 2x2; wave tile (TM*16)x(TN*16) of 16x16x32 bf16 MFMAs.
// MODE 0: generic z-strided. MODE 1: QK^T per z=(b*12+h). MODE 2: PV per z.
template <int BM, int BN, int MODE, bool BIAS, bool GELU_ACT, bool OUT_BF16>
__global__ __launch_bounds__(256) void gemm_nt(const ushort* __restrict__ Ab, int lda, long long sAz,
                                               const ushort* __restrict__ Bb, int ldb, long long sBz,
                                               void* __restrict__ Cb, int ldc, long long sCz,
                                               const float* __restrict__ bias,
                                               int M, int N, int K, float scale) {
    constexpr int BK = 32;               // 64 B per LDS row, unpadded (global_load_lds layout)
    constexpr int TM = BM / 32, TN = BN / 32;
    __shared__ __align__(16) ushort As[BM * BK];
    __shared__ __align__(16) ushort Bs[BN * BK];

    int z = blockIdx.z;
    const ushort* A = Ab;
    const ushort* B = Bb;
    char* C = (char*)Cb;
    if (MODE == 0) {
        A += (size_t)z * sAz;
        B += (size_t)z * sBz;
        C += (size_t)z * sCz * (OUT_BF16 ? 2 : 4);
    } else if (MODE == 1) {              // QK^T: A=q slice, B=k slice, C=logits[z]
        int b = z / 12, hh = z % 12;
        size_t qo = (size_t)(b * 197) * 768 + hh * 64;
        A += qo; B += qo;
        C += (size_t)z * 197 * 224 * 2;
    } else {                             // PV: A=probs[z], B=vT[z], C=o slice
        int b = z / 12, hh = z % 12;
        A += (size_t)z * 197 * 224;
        B += (size_t)z * 64 * 224;
        C += ((size_t)(b * 197) * 768 + hh * 64) * 2;
    }

    int tid = threadIdx.x;
    int lane = tid & 63, wave = tid >> 6;
    int wr = wave >> 1, wc = wave & 1;
    int qq = lane >> 4, rr = lane & 15;
    int lrow = lane >> 2, lck = lane & 3;     // staging: 16 rows x 4 chunks per wave-issue
    int tileM = blockIdx.y * BM, tileN = blockIdx.x * BN;

    f32x4 acc[TM][TN] = {};

    for (int k0 = 0; k0 < K; k0 += BK) {
        // stage A: BM rows x 64 B; each wave-issue = 16 rows (1 KB)
#pragma unroll
        for (int it = 0; it < BM / 64; it++) {
            int base_row = (it * 4 + wave) * 16;
            int gr = tileM + base_row + lrow;
            if (gr >= M) gr = M - 1;
            async_copy16(A + (size_t)gr * lda + k0 + lck * 8, As + base_row * BK);
        }
        // stage B (BT rows = output cols)
#pragma unroll
        for (int it = 0; it < BN / 64; it++) {
            int base_row = (it * 4 + wave) * 16;
            int gr = tileN + base_row + lrow;
            if (gr >= N) gr = N - 1;
            async_copy16(B + (size_t)gr * ldb + k0 + lck * 8, Bs + base_row * BK);
        }
        __syncthreads();                 // drains vmcnt (global_load_lds) + joins waves
        bf16x8 af[TM], bfr[TN];
#pragma unroll
        for (int i = 0; i < TM; i++)
            af[i] = *(const bf16x8*)(&As[(wr * TM * 16 + i * 16 + rr) * BK + qq * 8]);
#pragma unroll
        for (int j = 0; j < TN; j++)
            bfr[j] = *(const bf16x8*)(&Bs[(wc * TN * 16 + j * 16 + rr) * BK + qq * 8]);
#pragma unroll
        for (int i = 0; i < TM; i++)
#pragma unroll
            for (int j = 0; j < TN; j++)
                acc[i][j] = __builtin_amdgcn_mfma_f32_16x16x32_bf16(af[i], bfr[j], acc[i][j], 0, 0, 0);
        __syncthreads();
    }

    // epilogue: C/D layout col = lane&15, row = (lane>>4)*4 + reg
#pragma unroll
    for (int i = 0; i < TM; i++) {
        int rowb = tileM + wr * TM * 16 + i * 16 + qq * 4;
#pragma unroll
        for (int j = 0; j < TN; j++) {
            int colg = tileN + wc * TN * 16 + j * 16 + rr;
            if (colg >= N) continue;
            float bv = BIAS ? bias[colg] : 0.0f;
#pragma unroll
            for (int rg = 0; rg < 4; rg++) {
                int rowg = rowb + rg;
                if (rowg >= M) continue;
                float c = acc[i][j][rg] * scale + bv;
                if (GELU_ACT) c = 0.5f * c * (1.0f + erff(c * 0.70710678118654752f));
                if (OUT_BF16)
                    ((ushort*)C)[(size_t)rowg * ldc + colg] = f2bf(c);
                else
                    ((float*)C)[(size_t)rowg * ldc + colg] = c;
            }
        }
    }
}

// ---------------- host ----------------

extern "C" void kernel_launch(void* const* d_in, const int* in_sizes, int n_in,
                              void* d_out, int out_size, void* d_ws, size_t ws_size,
                              hipStream_t stream) {
    const float* img     = (const float*)d_in[0];
    const float* patch_w = (const float*)d_in[1];
    const float* patch_b = (const float*)d_in[2];
    const float* cls_tok = (const float*)d_in[3];
    const float* Wq      = (const float*)d_in[4];
    const float* Wk      = (const float*)d_in[5];
    const float* Wv      = (const float*)d_in[6];
    const float* Wo      = (const float*)d_in[7];
    const float* bo      = (const float*)d_in[8];
    const float* ln1_g   = (const float*)d_in[9];
    const float* ln1_b   = (const float*)d_in[10];
    const float* fln_g   = (const float*)d_in[11];
    const float* fln_b   = (const float*)d_in[12];
    const float* fc1_w   = (const float*)d_in[13];
    const float* fc1_b   = (const float*)d_in[14];
    const float* fc2_w   = (const float*)d_in[15];
    const float* fc2_b   = (const float*)d_in[16];
    const float* ln2_g   = (const float*)d_in[17];
    const float* ln2_b   = (const float*)d_in[18];
    const float* clf_w   = (const float*)d_in[19];
    const float* clf_b   = (const float*)d_in[20];

    const size_t EE = (size_t)768 * 768;     // 589824
    const int MROWS = 32 * 197;              // 6304

    char* ws = (char*)d_ws;
    size_t off = 0;
    auto alloc = [&](size_t bytes) { size_t o = off; off += (bytes + 255) & ~(size_t)255; return o; };
    size_t o_wT     = alloc(48 * EE * 2);                    // [wqT|wkT|wvT|woT] x 12 layers
    size_t o_patchT = alloc(EE * 2);
    size_t o_fc1T   = alloc((size_t)12 * 768 * 3072 * 2);    // [3072][768] per layer
    size_t o_fc2T   = alloc((size_t)12 * 768 * 3072 * 2);    // [768][3072] per layer
    size_t o_patch  = alloc((size_t)6272 * 768 * 2);
    size_t o_x      = alloc((size_t)MROWS * 768 * 4);
    size_t o_xb     = alloc((size_t)MROWS * 768 * 2);
    size_t o_xf     = alloc((size_t)MROWS * 768 * 2);
    size_t o_qkv    = alloc((size_t)3 * MROWS * 768 * 2);
    size_t o_y      = alloc((size_t)MROWS * 768 * 4);
    size_t o_o      = alloc((size_t)MROWS * 768 * 2);
    size_t logitsB  = (size_t)384 * 197 * 224 * 2;           // 33,890,304
    size_t vTB      = (size_t)384 * 64 * 224 * 2;            // 11,010,048
    size_t hB       = (size_t)MROWS * 3072 * 2;              // 38,731,776
    size_t unionB   = (logitsB + vTB > hB) ? logitsB + vTB : hB;
    size_t o_attn   = alloc(unionB);
    if (off > ws_size) return;                               // ws too small: clean fail

    ushort* wT     = (ushort*)(ws + o_wT);
    ushort* patchT = (ushort*)(ws + o_patchT);
    ushort* fc1T   = (ushort*)(ws + o_fc1T);
    ushort* fc2T   = (ushort*)(ws + o_fc2T);
    ushort* patches= (ushort*)(ws + o_patch);
    float*  x      = (float*)(ws + o_x);
    ushort* xb     = (ushort*)(ws + o_xb);
    ushort* xf     = (ushort*)(ws + o_xf);
    ushort* qkv    = (ushort*)(ws + o_qkv);
    float*  y      = (float*)(ws + o_y);
    ushort* o_     = (ushort*)(ws + o_o);
    ushort* logits = (ushort*)(ws + o_attn);
    ushort* vT     = (ushort*)(ws + o_attn + logitsB);
    ushort* h      = (ushort*)(ws + o_attn);

    dim3 tb(32, 8);
    transpose_w_k<<<dim3(24, 24, 1),  tb, 0, stream>>>(patch_w, patchT, 768, 768);
    transpose_w_k<<<dim3(24, 24, 12), tb, 0, stream>>>(Wq, wT + 0 * 12 * EE, 768, 768);
    transpose_w_k<<<dim3(24, 24, 12), tb, 0, stream>>>(Wk, wT + 1 * 12 * EE, 768, 768);
    transpose_w_k<<<dim3(24, 24, 12), tb, 0, stream>>>(Wv, wT + 2 * 12 * EE, 768, 768);
    transpose_w_k<<<dim3(24, 24, 12), tb, 0, stream>>>(Wo, wT + 3 * 12 * EE, 768, 768);
    transpose_w_k<<<dim3(96, 24, 12), tb, 0, stream>>>(fc1_w, fc1T, 768, 3072);
    transpose_w_k<<<dim3(24, 96, 12), tb, 0, stream>>>(fc2_w, fc2T, 3072, 768);

    patchify_k<<<18816, 256, 0, stream>>>(img, patches);
    gemm_nt<128, 128, 0, true, false, false><<<dim3(6, 49, 1), 256, 0, stream>>>(
        patches, 768, 0, patchT, 768, 0, y, 768, 0, patch_b, 6272, 768, 768, 1.0f);
    assemble_k<<<18912, 256, 0, stream>>>(y, cls_tok, x, xb);

    for (int l = 0; l < 12; ++l) {
        gemm_nt<128, 128, 0, false, false, true><<<dim3(6, 50, 3), 256, 0, stream>>>(
            xb, 768, 0, wT + (size_t)l * EE, 768, (long long)(12 * EE),
            qkv, 768, (long long)MROWS * 768, nullptr, MROWS, 768, 768, 1.0f);
        transpose_v_k<<<dim3(7, 2, 384), tb, 0, stream>>>(qkv + (size_t)2 * MROWS * 768, vT);
        gemm_nt<64, 64, 1, false, false, true><<<dim3(4, 4, 384), 256, 0, stream>>>(
            qkv, 768, 0, qkv + (size_t)MROWS * 768, 768, 0,
            logits, 224, 0, nullptr, 197, 197, 64, 0.125f);
        softmax_k<<<dim3(197, 384), 64, 0, stream>>>(logits);
        gemm_nt<64, 64, 2, false, false, true><<<dim3(1, 4, 384), 256, 0, stream>>>(
            logits, 224, 0, vT, 224, 0, o_, 768, 0, nullptr, 197, 64, 224, 1.0f);
        gemm_nt<128, 128, 0, true, false, false><<<dim3(6, 50, 1), 256, 0, stream>>>(
            o_, 768, 0, wT + (size_t)(36 + l) * EE, 768, 0,
            y, 768, 0, bo + l * 768, MROWS, 768, 768, 1.0f);
        ln_kernel<<<MROWS, 256, 0, stream>>>(y, x, xb, xf, ln1_g + l * 768, ln1_b + l * 768,
                                             fln_g + l * 768, fln_b + l * 768, 1);
        gemm_nt<128, 128, 0, true, true, true><<<dim3(24, 50, 1), 256, 0, stream>>>(
            xf, 768, 0, fc1T + (size_t)l * 768 * 3072, 768, 0,
            h, 3072, 0, fc1_b + l * 3072, MROWS, 3072, 768, 1.0f);
        gemm_nt<128, 128, 0, true, false, false><<<dim3(6, 50, 1), 256, 0, stream>>>(
            h, 3072, 0, fc2T + (size_t)l * 768 * 3072, 3072, 0,
            y, 768, 0, fc2_b + l * 768, MROWS, 768, 3072, 1.0f);
        ln_kernel<<<MROWS, 256, 0, stream>>>(y, x, xb, nullptr, ln2_g + l * 768, ln2_b + l * 768,
                                             nullptr, nullptr, 0);
    }

    classifier_k<<<32, 256, 0, stream>>>(x, clf_w, clf_b, (float*)d_out);
}

// Round 3
// 4294.118 us; speedup vs baseline: 1.4359x; 1.0945x over previous
//
#include <hip/hip_runtime.h>

// ---------------- common helpers ----------------

using bf16x8 = __attribute__((ext_vector_type(8))) short;   // 8 bf16 (4 VGPRs)
using f32x4  = __attribute__((ext_vector_type(4))) float;   // 4 fp32 acc

struct CPtrs { void* p[3]; };            // split-K partial C pointers

__device__ __forceinline__ ushort f2bf(float f) {            // fp32 -> bf16 RNE
    unsigned u = __float_as_uint(f);
    u += 0x7FFFu + ((u >> 16) & 1u);
    return (ushort)(u >> 16);
}
__device__ __forceinline__ float bf2f(ushort h) {
    return __uint_as_float((unsigned)h << 16);
}

// async 16B global -> LDS (wave-uniform LDS base + lane*16B)
__device__ __forceinline__ void async_copy16(const ushort* g, ushort* l) {
    __builtin_amdgcn_global_load_lds(
        (const __attribute__((address_space(1))) void*)g,
        (__attribute__((address_space(3))) void*)l, 16, 0, 0);
}

// block = 256 threads (4 waves). Reduces two values across the block.
__device__ __forceinline__ void blockReduce2(float& a, float& b, float* sh) {
#pragma unroll
    for (int off = 32; off > 0; off >>= 1) {
        a += __shfl_down(a, off, 64);
        b += __shfl_down(b, off, 64);
    }
    int wave = threadIdx.x >> 6, lane = threadIdx.x & 63;
    __syncthreads();
    if (lane == 0) { sh[wave] = a; sh[4 + wave] = b; }
    __syncthreads();
    a = sh[0] + sh[1] + sh[2] + sh[3];
    b = sh[4] + sh[5] + sh[6] + sh[7];
}

// ---------------- weight transpose (fp32 [K][N] -> bf16 [N][K]) ----------------
__global__ void transpose_w_k(const float* __restrict__ in, ushort* __restrict__ out,
                              int K, int N) {
    __shared__ float tile[32][33];
    size_t zoff = (size_t)blockIdx.z * K * N;
    in += zoff; out += zoff;
    int n0 = blockIdx.x * 32, k0 = blockIdx.y * 32;
    int tx = threadIdx.x, ty = threadIdx.y;
#pragma unroll
    for (int i = 0; i < 4; i++)
        tile[ty + i * 8][tx] = in[(size_t)(k0 + ty + i * 8) * N + n0 + tx];
    __syncthreads();
#pragma unroll
    for (int i = 0; i < 4; i++)
        out[(size_t)(n0 + ty + i * 8) * K + k0 + tx] = f2bf(tile[tx][ty + i * 8]);
}

// ---------------- V transpose per (b,h): v[b,s,h,d] -> vT[z][d][s(pad 224)] ---------
__global__ void transpose_v_k(const ushort* __restrict__ v, ushort* __restrict__ vT) {
    __shared__ ushort tile[32][33];
    int z = blockIdx.z, b = z / 12, hh = z % 12;
    int s0 = blockIdx.x * 32, d0 = blockIdx.y * 32;
    int tx = threadIdx.x, ty = threadIdx.y;
#pragma unroll
    for (int i = 0; i < 4; i++) {
        int s = s0 + ty + i * 8;
        tile[ty + i * 8][tx] =
            (s < 197) ? v[((size_t)(b * 197 + s)) * 768 + hh * 64 + d0 + tx] : (ushort)0;
    }
    __syncthreads();
#pragma unroll
    for (int i = 0; i < 4; i++) {
        int d = d0 + ty + i * 8;
        vT[(size_t)z * 64 * 224 + (size_t)d * 224 + s0 + tx] = tile[tx][ty + i * 8];
    }
}

// ---------------- patchify: img [32,3,224,224] -> patches bf16 [6272][768] ----------
__global__ __launch_bounds__(256) void patchify_k(const float* __restrict__ img,
                                                  ushort* __restrict__ patches) {
    int idx = blockIdx.x * 256 + threadIdx.x;
    int e = idx % 768, pr = idx / 768;
    int b = pr / 196, p = pr % 196;
    int ph = p / 14, pw = p % 14;
    int c = e % 3, pe = e / 3;
    int p1 = pe >> 4, p2 = pe & 15;
    float v = img[((size_t)(b * 3 + c) * 224 + ph * 16 + p1) * 224 + pw * 16 + p2];
    patches[idx] = f2bf(v);
}

// ---------------- assemble x = [cls | patch_tokens + posenc] -> x fp32 + bf16 -------
__global__ __launch_bounds__(256) void assemble_k(const float* __restrict__ y,
                                                  const float* __restrict__ cls,
                                                  float* __restrict__ x,
                                                  ushort* __restrict__ xb) {
    int idx = blockIdx.x * 256 + threadIdx.x;
    int e = idx % 768, rr = idx / 768;
    int b = rr / 197, s = rr % 197;
    float val;
    if (s == 0) {
        val = cls[e];
    } else {
        int p = s - 1, iy = p / 14, ix = p % 14;
        int j = e % 192, g = e / 192;
        float om = powf(10000.f, -(float)j * (1.0f / 191.0f));
        float arg = ((g & 2) ? (float)iy : (float)ix) * om;
        float pe = (g & 1) ? cosf(arg) : sinf(arg);
        val = y[(size_t)(b * 196 + p) * 768 + e] + pe;
    }
    x[idx] = val;
    xb[idx] = f2bf(val);
}

// ---------------- fused split-K reduce + gemm-bias + residual + LN ------------------
// t = x + gb + y0 [+ y1 [+ y2]];  x = LN(t, g1, b1)
// WXB: write bf16(x) to xb.  SECOND: xf = bf16(LN(x, gf, bfv)).
template <int NP, bool SECOND, bool WXB>
__global__ __launch_bounds__(256) void ln_kernel(const float* __restrict__ y0,
                                                 const float* __restrict__ y1,
                                                 const float* __restrict__ y2,
                                                 const float* __restrict__ gb,
                                                 float* __restrict__ x,
                                                 ushort* __restrict__ xb,
                                                 ushort* __restrict__ xf,
                                                 const float* __restrict__ g1,
                                                 const float* __restrict__ b1,
                                                 const float* __restrict__ gf,
                                                 const float* __restrict__ bfv) {
    __shared__ float red[8];
    int row = blockIdx.x, tid = threadIdx.x;
    size_t base = (size_t)row * 768;
    float* xr = x + base;
    float v0[3], s = 0.f, ss = 0.f;
#pragma unroll
    for (int i = 0; i < 3; i++) {
        int c = tid + i * 256;
        float t = xr[c] + gb[c] + y0[base + c];
        if (NP > 1) t += y1[base + c];
        if (NP > 2) t += y2[base + c];
        v0[i] = t; s += t; ss += t * t;
    }
    blockReduce2(s, ss, red);
    float m = s * (1.f / 768.f);
    float var = ss * (1.f / 768.f) - m * m;
    float rstd = rsqrtf(var + 1e-5f);
    float s2 = 0.f, ss2 = 0.f, w0[3];
#pragma unroll
    for (int i = 0; i < 3; i++) {
        int c = tid + i * 256;
        float xv = (v0[i] - m) * rstd * g1[c] + b1[c];
        w0[i] = xv;
        xr[c] = xv;
        if (WXB) xb[base + c] = f2bf(xv);
        s2 += xv; ss2 += xv * xv;
    }
    if (SECOND) {
        blockReduce2(s2, ss2, red);
        float m2 = s2 * (1.f / 768.f);
        float var2 = ss2 * (1.f / 768.f) - m2 * m2;
        float r2 = rsqrtf(var2 + 1e-5f);
#pragma unroll
        for (int i = 0; i < 3; i++) {
            int c = tid + i * 256;
            xf[base + c] = f2bf((w0[i] - m2) * r2 * gf[c] + bfv[c]);
        }
    }
}

// ---------------- softmax, in-place bf16, rows of [197 valid | 224 padded] ----------
__global__ __launch_bounds__(64) void softmax_k(ushort* __restrict__ logits) {
    int s = blockIdx.x, z = blockIdx.y, lane = threadIdx.x;
    ushort* row = logits + ((size_t)z * 197 + s) * 224;
    float v[4], mx = -1e30f;
#pragma unroll
    for (int i = 0; i < 4; i++) {
        int c = lane + i * 64;
        float t = -1e30f;
        if (c < 197) t = bf2f(row[c]);
        v[i] = t; mx = fmaxf(mx, t);
    }
#pragma unroll
    for (int off = 32; off > 0; off >>= 1) mx = fmaxf(mx, __shfl_xor(mx, off, 64));
    float sum = 0.f;
#pragma unroll
    for (int i = 0; i < 4; i++) {
        int c = lane + i * 64;
        float ev = 0.f;
        if (c < 197) ev = expf(v[i] - mx);
        v[i] = ev; sum += ev;
    }
#pragma unroll
    for (int off = 32; off > 0; off >>= 1) sum += __shfl_xor(sum, off, 64);
    float inv = 1.f / sum;
#pragma unroll
    for (int i = 0; i < 4; i++) {
        int c = lane + i * 64;
        if (c < 224) row[c] = f2bf(c < 197 ? v[i] * inv : 0.f);
    }
}

// ---------------- classifier ----------------
__global__ __launch_bounds__(256) void classifier_k(const float* __restrict__ x,
                                                    const float* __restrict__ w,
                                                    const float* __restrict__ bias,
                                                    float* __restrict__ out) {
    __shared__ float red[8];
    int b = blockIdx.x, tid = threadIdx.x;
    const float* xr = x + (size_t)b * 197 * 768;
    float s0 = 0.f, s1 = 0.f;
    for (int e = tid; e < 768; e += 256) {
        float xv = xr[e];
        s0 += xv * w[2 * e];
        s1 += xv * w[2 * e + 1];
    }
    blockReduce2(s0, s1, red);
    if (tid == 0) {
        out[2 * b] = s0 + bias[0];
        out[2 * b + 1] = s1 + bias[1];
    }
}

// ---------------- NT GEMM (m97-style): C = act(A[M,K] . BT[N,K]^T * scale + bias) ----
// Staging via global_load_lds width=16 into UNPADDED LDS (BK=32 -> 64 B/row).
// MODE 0: generic z-strided batch. MODE 1: QK^T per z=(b,h). MODE 2: PV per z.
// MODE 3: split-K — z = K-slice; A += z*sAz, B += z*sBz (element offsets into the
//         K dim), C = cps.p[z] (fp32 partial buffers, reduced later in ln_kernel).
template <int BM, int BN, int MODE, bool BIAS, bool GELU_ACT, bool OUT_BF16>
__global__ __launch_bounds__(256) void gemm_nt(const ushort* __restrict__ Ab, int lda, long long sAz,
                                               const ushort* __restrict__ Bb, int ldb, long long sBz,
                                               void* __restrict__ Cb, int ldc, long long sCz,
                                               const float* __restrict__ bias,
                                               int M, int N, int K, float scale, CPtrs cps) {
    constexpr int BK = 32;               // 64 B per LDS row, unpadded (global_load_lds layout)
    constexpr int TM = BM / 32, TN = BN / 32;
    __shared__ __align__(16) ushort As[BM * BK];
    __shared__ __align__(16) ushort Bs[BN * BK];

    int z = blockIdx.z;
    const ushort* A = Ab;
    const ushort* B = Bb;
    char* C = (char*)Cb;
    if (MODE == 0) {
        A += (size_t)z * sAz;
        B += (size_t)z * sBz;
        C += (size_t)z * sCz * (OUT_BF16 ? 2 : 4);
    } else if (MODE == 1) {              // QK^T
        int b = z / 12, hh = z % 12;
        size_t qo = (size_t)(b * 197) * 768 + hh * 64;
        A += qo; B += qo;
        C += (size_t)z * 197 * 224 * 2;
    } else if (MODE == 2) {              // PV
        int b = z / 12, hh = z % 12;
        A += (size_t)z * 197 * 224;
        B += (size_t)z * 64 * 224;
        C += ((size_t)(b * 197) * 768 + hh * 64) * 2;
    } else {                             // split-K
        A += (size_t)z * sAz;
        B += (size_t)z * sBz;
        C = (char*)cps.p[z];
    }

    int tid = threadIdx.x;
    int lane = tid & 63, wave = tid >> 6;
    int wr = wave >> 1, wc = wave & 1;
    int qq = lane >> 4, rr = lane & 15;
    int lrow = lane >> 2, lck = lane & 3;     // staging: 16 rows x 4 chunks per wave-issue
    int tileM = blockIdx.y * BM, tileN = blockIdx.x * BN;

    f32x4 acc[TM][TN] = {};

    for (int k0 = 0; k0 < K; k0 += BK) {
#pragma unroll
        for (int it = 0; it < BM / 64; it++) {
            int base_row = (it * 4 + wave) * 16;
            int gr = tileM + base_row + lrow;
            if (gr >= M) gr = M - 1;
            async_copy16(A + (size_t)gr * lda + k0 + lck * 8, As + base_row * BK);
        }
#pragma unroll
        for (int it = 0; it < BN / 64; it++) {
            int base_row = (it * 4 + wave) * 16;
            int gr = tileN + base_row + lrow;
            if (gr >= N) gr = N - 1;
            async_copy16(B + (size_t)gr * ldb + k0 + lck * 8, Bs + base_row * BK);
        }
        __syncthreads();
        bf16x8 af[TM], bfr[TN];
#pragma unroll
        for (int i = 0; i < TM; i++)
            af[i] = *(const bf16x8*)(&As[(wr * TM * 16 + i * 16 + rr) * BK + qq * 8]);
#pragma unroll
        for (int j = 0; j < TN; j++)
            bfr[j] = *(const bf16x8*)(&Bs[(wc * TN * 16 + j * 16 + rr) * BK + qq * 8]);
#pragma unroll
        for (int i = 0; i < TM; i++)
#pragma unroll
            for (int j = 0; j < TN; j++)
                acc[i][j] = __builtin_amdgcn_mfma_f32_16x16x32_bf16(af[i], bfr[j], acc[i][j], 0, 0, 0);
        __syncthreads();
    }

    // epilogue: C/D layout col = lane&15, row = (lane>>4)*4 + reg
#pragma unroll
    for (int i = 0; i < TM; i++) {
        int rowb = tileM + wr * TM * 16 + i * 16 + qq * 4;
#pragma unroll
        for (int j = 0; j < TN; j++) {
            int colg = tileN + wc * TN * 16 + j * 16 + rr;
            if (colg >= N) continue;
            float bv = BIAS ? bias[colg] : 0.0f;
#pragma unroll
            for (int rg = 0; rg < 4; rg++) {
                int rowg = rowb + rg;
                if (rowg >= M) continue;
                float c = acc[i][j][rg] * scale + bv;
                if (GELU_ACT) c = 0.5f * c * (1.0f + erff(c * 0.70710678118654752f));
                if (OUT_BF16)
                    ((ushort*)C)[(size_t)rowg * ldc + colg] = f2bf(c);
                else
                    ((float*)C)[(size_t)rowg * ldc + colg] = c;
            }
        }
    }
}

// ---------------- host ----------------

extern "C" void kernel_launch(void* const* d_in, const int* in_sizes, int n_in,
                              void* d_out, int out_size, void* d_ws, size_t ws_size,
                              hipStream_t stream) {
    const float* img     = (const float*)d_in[0];
    const float* patch_w = (const float*)d_in[1];
    const float* patch_b = (const float*)d_in[2];
    const float* cls_tok = (const float*)d_in[3];
    const float* Wq      = (const float*)d_in[4];
    const float* Wk      = (const float*)d_in[5];
    const float* Wv      = (const float*)d_in[6];
    const float* Wo      = (const float*)d_in[7];
    const float* bo      = (const float*)d_in[8];
    const float* ln1_g   = (const float*)d_in[9];
    const float* ln1_b   = (const float*)d_in[10];
    const float* fln_g   = (const float*)d_in[11];
    const float* fln_b   = (const float*)d_in[12];
    const float* fc1_w   = (const float*)d_in[13];
    const float* fc1_b   = (const float*)d_in[14];
    const float* fc2_w   = (const float*)d_in[15];
    const float* fc2_b   = (const float*)d_in[16];
    const float* ln2_g   = (const float*)d_in[17];
    const float* ln2_b   = (const float*)d_in[18];
    const float* clf_w   = (const float*)d_in[19];
    const float* clf_b   = (const float*)d_in[20];

    const size_t EE = (size_t)768 * 768;     // 589824
    const int MROWS = 32 * 197;              // 6304
    const size_t ROWB = (size_t)MROWS * 768; // elements per activation matrix

    char* ws = (char*)d_ws;
    size_t off = 0;
    auto alloc = [&](size_t bytes) { size_t o = off; off += (bytes + 255) & ~(size_t)255; return o; };
    size_t o_wT     = alloc(48 * EE * 2);
    size_t o_patchT = alloc(EE * 2);
    size_t o_fc1T   = alloc((size_t)12 * 768 * 3072 * 2);
    size_t o_fc2T   = alloc((size_t)12 * 768 * 3072 * 2);
    size_t o_patch  = alloc((size_t)6272 * 768 * 2);
    size_t o_x      = alloc(ROWB * 4);
    size_t o_xb     = alloc(ROWB * 2);
    // qkv, xf, o_ MUST be contiguous: they double as FC2 fp32 partial slices 1&2
    size_t o_qkv    = alloc(3 * ROWB * 2);   // 29,048,832 B (256-aligned)
    size_t o_xf     = alloc(ROWB * 2);       //  9,682,944 B (256-aligned)
    size_t o_o      = alloc(ROWB * 2);
    size_t o_y      = alloc(ROWB * 4);       // split-K slice 0 (Wo & FC2)
    size_t logitsB  = (size_t)384 * 197 * 224 * 2;
    size_t vTB      = (size_t)384 * 64 * 224 * 2;
    size_t hB       = 3 * ROWB * 2 * 2;      // h: 6304 x 3072 bf16 = 38.7MB
    size_t unionB   = (logitsB + vTB > hB) ? logitsB + vTB : hB;
    size_t o_attn   = alloc(unionB);
    if (off > ws_size) return;

    ushort* wT     = (ushort*)(ws + o_wT);
    ushort* patchT = (ushort*)(ws + o_patchT);
    ushort* fc1T   = (ushort*)(ws + o_fc1T);
    ushort* fc2T   = (ushort*)(ws + o_fc2T);
    ushort* patches= (ushort*)(ws + o_patch);
    float*  x      = (float*)(ws + o_x);
    ushort* xb     = (ushort*)(ws + o_xb);
    ushort* xf     = (ushort*)(ws + o_xf);
    ushort* qkv    = (ushort*)(ws + o_qkv);
    float*  y      = (float*)(ws + o_y);
    ushort* o_     = (ushort*)(ws + o_o);
    ushort* logits = (ushort*)(ws + o_attn);
    ushort* vT     = (ushort*)(ws + o_attn + logitsB);
    ushort* h      = (ushort*)(ws + o_attn);
    // split-K partial slices (fp32, each ROWB*4 = 19,365,888 B):
    float* woP1  = (float*)(ws + o_attn);                    // attn scratch dead at Wo time
    float* fc2P1 = (float*)(ws + o_qkv);                     // qkv dead during MLP
    float* fc2P2 = (float*)(ws + o_qkv + ROWB * 4);          // spans qkv tail + xf (contiguous)

    CPtrs cN{}; CPtrs cWo{{y, woP1, nullptr}}; CPtrs cF2{{y, fc2P1, fc2P2}};

    dim3 tb(32, 8);
    transpose_w_k<<<dim3(24, 24, 1),  tb, 0, stream>>>(patch_w, patchT, 768, 768);
    transpose_w_k<<<dim3(24, 24, 12), tb, 0, stream>>>(Wq, wT + 0 * 12 * EE, 768, 768);
    transpose_w_k<<<dim3(24, 24, 12), tb, 0, stream>>>(Wk, wT + 1 * 12 * EE, 768, 768);
    transpose_w_k<<<dim3(24, 24, 12), tb, 0, stream>>>(Wv, wT + 2 * 12 * EE, 768, 768);
    transpose_w_k<<<dim3(24, 24, 12), tb, 0, stream>>>(Wo, wT + 3 * 12 * EE, 768, 768);
    transpose_w_k<<<dim3(96, 24, 12), tb, 0, stream>>>(fc1_w, fc1T, 768, 3072);
    transpose_w_k<<<dim3(24, 96, 12), tb, 0, stream>>>(fc2_w, fc2T, 3072, 768);

    patchify_k<<<18816, 256, 0, stream>>>(img, patches);
    gemm_nt<128, 128, 0, true, false, false><<<dim3(6, 49, 1), 256, 0, stream>>>(
        patches, 768, 0, patchT, 768, 0, y, 768, 0, patch_b, 6272, 768, 768, 1.0f, cN);
    assemble_k<<<18912, 256, 0, stream>>>(y, cls_tok, x, xb);

    for (int l = 0; l < 12; ++l) {
        // QKV (z selects Wq/Wk/Wv), bf16 out
        gemm_nt<128, 128, 0, false, false, true><<<dim3(6, 50, 3), 256, 0, stream>>>(
            xb, 768, 0, wT + (size_t)l * EE, 768, (long long)(12 * EE),
            qkv, 768, (long long)ROWB, nullptr, MROWS, 768, 768, 1.0f, cN);
        transpose_v_k<<<dim3(7, 2, 384), tb, 0, stream>>>(qkv + 2 * ROWB, vT);
        gemm_nt<64, 64, 1, false, false, true><<<dim3(4, 4, 384), 256, 0, stream>>>(
            qkv, 768, 0, qkv + ROWB, 768, 0,
            logits, 224, 0, nullptr, 197, 197, 64, 0.125f, cN);
        softmax_k<<<dim3(197, 384), 64, 0, stream>>>(logits);
        gemm_nt<64, 64, 2, false, false, true><<<dim3(1, 4, 384), 256, 0, stream>>>(
            logits, 224, 0, vT, 224, 0, o_, 768, 0, nullptr, 197, 64, 224, 1.0f, cN);
        // Wo: split-K x2 (chunks of 384), fp32 partials y + woP1; bias bo in LN1
        gemm_nt<128, 128, 3, false, false, false><<<dim3(6, 50, 2), 256, 0, stream>>>(
            o_, 768, 384, wT + (size_t)(36 + l) * EE, 768, 384,
            nullptr, 768, 0, nullptr, MROWS, 768, 384, 1.0f, cWo);
        // x = LN(x + bo + y + woP1);  xf = bf16(LN(x, fln))
        ln_kernel<2, true, false><<<MROWS, 256, 0, stream>>>(
            y, woP1, nullptr, bo + l * 768, x, nullptr, xf,
            ln1_g + l * 768, ln1_b + l * 768, fln_g + l * 768, fln_b + l * 768);
        // h = gelu(xf @ w1 + b1)
        gemm_nt<128, 128, 0, true, true, true><<<dim3(24, 50, 1), 256, 0, stream>>>(
            xf, 768, 0, fc1T + (size_t)l * 768 * 3072, 768, 0,
            h, 3072, 0, fc1_b + l * 3072, MROWS, 3072, 768, 1.0f, cN);
        // FC2: split-K x3 (chunks of 1024), fp32 partials y + fc2P1 + fc2P2; bias in LN2
        gemm_nt<128, 128, 3, false, false, false><<<dim3(6, 50, 3), 256, 0, stream>>>(
            h, 3072, 1024, fc2T + (size_t)l * 768 * 3072, 3072, 1024,
            nullptr, 768, 0, nullptr, MROWS, 768, 1024, 1.0f, cF2);
        // x = LN(x + b2 + y + fc2P1 + fc2P2); xb = bf16(x)
        ln_kernel<3, false, true><<<MROWS, 256, 0, stream>>>(
            y, fc2P1, fc2P2, fc2_b + l * 768, x, xb, nullptr,
            ln2_g + l * 768, ln2_b + l * 768, nullptr, nullptr);
    }

    classifier_k<<<32, 256, 0, stream>>>(x, clf_w, clf_b, (float*)d_out);
}